// Round 2
// baseline (1016.231 us; speedup 1.0000x reference)
//
#include <hip/hip_runtime.h>
#include <math.h>

#define D 128
#define A 5
#define TM 64
#define CSTR 68   // padded LDS stride for 64-wide combined tile (68*4B = 272B, 16B-aligned rows)

// ---------------- Kernel 1: node prompt + per-node edge-logit tables ----------------
// Computes node_px = x + softmax(x@attn_w + attn_b) @ anchor_node, and ALSO the
// rank-factored edge logit tables lsrc = x @ w_w[0:D], ldst = x @ w_w[D:2D]
// (x is already in registers here; 10 extra shuffle-reductions per node).
__global__ __launch_bounds__(256) void node_prompt_kernel(
    const float* __restrict__ x,
    const float* __restrict__ attn_w, const float* __restrict__ attn_b,
    const float* __restrict__ anchor_node,
    const float* __restrict__ w_w,
    float* __restrict__ node_px,
    float* __restrict__ lsrc, float* __restrict__ ldst, int N)
{
    int t = threadIdx.x;
    int lane = t & 63;
    int j = lane * 2;
    // Per-lane weight slices, loaded once into registers.
    float At0[A], At1[A], AN0[A], AN1[A], Ab[A];
    float W0[A], W1[A], W2[A], W3[A];
    #pragma unroll
    for (int a = 0; a < A; a++) {
        At0[a] = attn_w[(size_t)j * A + a];
        At1[a] = attn_w[(size_t)(j + 1) * A + a];
        AN0[a] = anchor_node[a * D + j];
        AN1[a] = anchor_node[a * D + j + 1];
        Ab[a]  = attn_b[a];
        W0[a]  = w_w[(size_t)j * A + a];
        W1[a]  = w_w[(size_t)(j + 1) * A + a];
        W2[a]  = w_w[(size_t)(D + j) * A + a];
        W3[a]  = w_w[(size_t)(D + j + 1) * A + a];
    }
    int wid = blockIdx.x * 4 + (t >> 6);
    int nw  = gridDim.x * 4;
    for (int n = wid; n < N; n += nw) {
        float2 xv = *(const float2*)&x[(size_t)n * D + j];
        float l[A], es[A], ed[A];
        #pragma unroll
        for (int a = 0; a < A; a++) {
            float p0 = xv.x * At0[a] + xv.y * At1[a];
            float p1 = xv.x * W0[a]  + xv.y * W1[a];
            float p2 = xv.x * W2[a]  + xv.y * W3[a];
            #pragma unroll
            for (int off = 32; off; off >>= 1) {
                p0 += __shfl_xor(p0, off);
                p1 += __shfl_xor(p1, off);
                p2 += __shfl_xor(p2, off);
            }
            l[a]  = p0 + Ab[a];
            es[a] = p1;
            ed[a] = p2;
        }
        float m = l[0];
        #pragma unroll
        for (int a = 1; a < A; a++) m = fmaxf(m, l[a]);
        float s = 0.f;
        #pragma unroll
        for (int a = 0; a < A; a++) { l[a] = __expf(l[a] - m); s += l[a]; }
        float inv = 1.f / s;
        float2 o = xv;
        #pragma unroll
        for (int a = 0; a < A; a++) {
            float w = l[a] * inv;
            o.x += w * AN0[a];
            o.y += w * AN1[a];
        }
        *(float2*)&node_px[(size_t)n * D + j] = o;
        // lanes 0..A-1 write the edge-logit table entries
        if (lane < A) {
            float vs = es[0], vd = ed[0];
            #pragma unroll
            for (int a = 1; a < A; a++) if (lane == a) { vs = es[a]; vd = ed[a]; }
            lsrc[(size_t)n * A + lane] = vs;
            ldst[(size_t)n * A + lane] = vd;
        }
    }
}

// ---------------- Kernel 2: edge softmax from tables + coalesced edge_prompt write ----------------
// One THREAD per edge (no wave shuffles, no x gathers). Phase 1: scalar 5-wide
// softmax from L2-resident lsrc/ldst tables, scatter 10 coefficient atomics into
// bagg, stash b in LDS. Phase 2: block cooperatively writes the 256 edge_prompt
// rows fully coalesced (each wave: 2 contiguous 512B rows per iteration).
__global__ __launch_bounds__(256) void edge_kernel(
    const int* __restrict__ ei,
    const float* __restrict__ lsrc, const float* __restrict__ ldst,
    const float* __restrict__ w_b, const float* __restrict__ anchor_edge,
    float* __restrict__ edge_prompt, float* __restrict__ bagg, int E)
{
    __shared__ float Bs[256 * A];
    int t = threadIdx.x;
    int cg = t & 31;   // column chunk (4 floats) this thread owns in phase 2
    float4 AEc[A];
    #pragma unroll
    for (int a = 0; a < A; a++) AEc[a] = *(const float4*)&anchor_edge[a * D + cg * 4];
    float Wb[A];
    #pragma unroll
    for (int a = 0; a < A; a++) Wb[a] = w_b[a];

    int base = blockIdx.x * 256;
    int e = base + t;
    if (e < E) {
        int s = ei[e];
        int d = ei[(size_t)E + e];
        const float* ps = &lsrc[(size_t)s * A];
        const float* pd = &ldst[(size_t)d * A];
        float l[A];
        #pragma unroll
        for (int a = 0; a < A; a++) {
            float p = ps[a] + pd[a] + Wb[a];
            l[a] = (p > 0.f) ? p : 0.01f * p;   // leaky_relu (slope 0.01)
        }
        float m = l[0];
        #pragma unroll
        for (int a = 1; a < A; a++) m = fmaxf(m, l[a]);
        float sum = 0.f;
        #pragma unroll
        for (int a = 0; a < A; a++) { l[a] = __expf(l[a] - m); sum += l[a]; }
        float inv = 1.f / sum;
        #pragma unroll
        for (int a = 0; a < A; a++) {
            float bv = l[a] * inv;
            Bs[t * A + a] = bv;
            atomicAdd(&bagg[(size_t)s * A + a], bv);
            atomicAdd(&bagg[(size_t)d * A + a], bv);
        }
    }
    __syncthreads();
    int eg = t >> 5;
    #pragma unroll 4
    for (int r = 0; r < 32; r++) {
        int row = eg * 32 + r;
        int e2 = base + row;
        if (e2 >= E) break;
        float b0 = Bs[row * A + 0];
        float b1 = Bs[row * A + 1];
        float b2 = Bs[row * A + 2];
        float b3 = Bs[row * A + 3];
        float b4 = Bs[row * A + 4];
        float4 rr;
        rr.x = b0 * AEc[0].x + b1 * AEc[1].x + b2 * AEc[2].x + b3 * AEc[3].x + b4 * AEc[4].x;
        rr.y = b0 * AEc[0].y + b1 * AEc[1].y + b2 * AEc[2].y + b3 * AEc[3].y + b4 * AEc[4].y;
        rr.z = b0 * AEc[0].z + b1 * AEc[1].z + b2 * AEc[2].z + b3 * AEc[3].z + b4 * AEc[4].z;
        rr.w = b0 * AEc[0].w + b1 * AEc[1].w + b2 * AEc[2].w + b3 * AEc[3].w + b4 * AEc[4].w;
        *(float4*)&edge_prompt[(size_t)e2 * D + cg * 4] = rr;
    }
}

// ---------------- Kernel 2b: agg = bagg @ anchor_edge  (N x A x D, tiny) ----------------
__global__ __launch_bounds__(256) void agg_kernel(
    const float* __restrict__ bagg, const float* __restrict__ anchor_edge,
    float* __restrict__ agg, int N)
{
    __shared__ float AE[A * D];
    int t = threadIdx.x;
    for (int f = t; f < A * D; f += 256) AE[f] = anchor_edge[f];
    __syncthreads();
    int total = N * (D / 4);   // float4 chunks
    for (int i = blockIdx.x * 256 + t; i < total; i += gridDim.x * 256) {
        int n = i >> 5;
        int c = (i & 31) * 4;
        const float* br = &bagg[(size_t)n * A];
        float b0 = br[0], b1 = br[1], b2 = br[2], b3 = br[3], b4 = br[4];
        float4 e0 = *(float4*)&AE[0 * D + c];
        float4 e1 = *(float4*)&AE[1 * D + c];
        float4 e2 = *(float4*)&AE[2 * D + c];
        float4 e3 = *(float4*)&AE[3 * D + c];
        float4 e4 = *(float4*)&AE[4 * D + c];
        float4 r;
        r.x = b0 * e0.x + b1 * e1.x + b2 * e2.x + b3 * e3.x + b4 * e4.x;
        r.y = b0 * e0.y + b1 * e1.y + b2 * e2.y + b3 * e3.y + b4 * e4.y;
        r.z = b0 * e0.z + b1 * e1.z + b2 * e2.z + b3 * e3.z + b4 * e4.z;
        r.w = b0 * e0.w + b1 * e1.w + b2 * e2.w + b3 * e3.w + b4 * e4.w;
        *(float4*)&agg[(size_t)n * D + c] = r;
    }
}

// ---------------- helper: 4x4 outer-product FMA ----------------
__device__ __forceinline__ void fma4(float4& acc, const float4 cv,
                                     const float4 w0, const float4 w1,
                                     const float4 w2, const float4 w3)
{
    acc.x += cv.x * w0.x + cv.y * w1.x + cv.z * w2.x + cv.w * w3.x;
    acc.y += cv.x * w0.y + cv.y * w1.y + cv.z * w2.y + cv.w * w3.y;
    acc.z += cv.x * w0.z + cv.y * w1.z + cv.z * w2.z + cv.w * w3.z;
    acc.w += cv.x * w0.w + cv.y * w1.w + cv.z * w2.w + cv.w * w3.w;
}

// ---------------- Kernel 3a: h = relu([node_px, agg] @ cd1_w + cd1_b) ----------------
__global__ __launch_bounds__(256) void cd1_kernel(
    const float* __restrict__ node_px, const float* __restrict__ agg,
    const float* __restrict__ cd1_w, const float* __restrict__ cd1_b,
    float* __restrict__ h, int N)
{
    __shared__ float Wt[64 * D];       // 32 KB
    __shared__ float Cn[TM * CSTR];    // 17.4 KB
    int t = threadIdx.x;
    int n0 = blockIdx.x * TM;
    int cg = t & 31, ng = t >> 5;
    int c0 = cg * 4;
    float4 acc[8];
    #pragma unroll
    for (int jj = 0; jj < 8; jj++) acc[jj] = make_float4(0.f, 0.f, 0.f, 0.f);

    for (int kt = 0; kt < 4; kt++) {
        int k0 = kt * 64;
        __syncthreads();
        const float4* Wg = (const float4*)(cd1_w + (size_t)k0 * D);
        float4* Wl = (float4*)Wt;
        #pragma unroll
        for (int i = 0; i < 8; i++) Wl[i * 256 + t] = Wg[i * 256 + t];
        const float* src = (k0 < 128) ? node_px : agg;
        int koff = k0 & 127;
        #pragma unroll
        for (int i = 0; i < 4; i++) {
            int f = i * 256 + t;
            int n = f >> 4, k4 = f & 15;
            int nn = n0 + n; if (nn >= N) nn = N - 1;
            float4 v = *(const float4*)&src[(size_t)nn * D + koff + k4 * 4];
            *(float4*)&Cn[n * CSTR + k4 * 4] = v;
        }
        __syncthreads();
        #pragma unroll 4
        for (int k4 = 0; k4 < 16; k4++) {
            float4 w0 = *(float4*)&Wt[(k4 * 4 + 0) * D + c0];
            float4 w1 = *(float4*)&Wt[(k4 * 4 + 1) * D + c0];
            float4 w2 = *(float4*)&Wt[(k4 * 4 + 2) * D + c0];
            float4 w3 = *(float4*)&Wt[(k4 * 4 + 3) * D + c0];
            #pragma unroll
            for (int jj = 0; jj < 8; jj++) {
                float4 cv = *(float4*)&Cn[(ng * 8 + jj) * CSTR + k4 * 4];
                fma4(acc[jj], cv, w0, w1, w2, w3);
            }
        }
    }
    float4 b = *(const float4*)&cd1_b[c0];
    #pragma unroll
    for (int jj = 0; jj < 8; jj++) {
        int n = n0 + ng * 8 + jj;
        if (n < N) {
            float4 r;
            r.x = fmaxf(acc[jj].x + b.x, 0.f);
            r.y = fmaxf(acc[jj].y + b.y, 0.f);
            r.z = fmaxf(acc[jj].z + b.z, 0.f);
            r.w = fmaxf(acc[jj].w + b.w, 0.f);
            *(float4*)&h[(size_t)n * D + c0] = r;
        }
    }
}

// ---------------- Kernel 3b: cs = sigmoid(h @ cd2_w + cd2_b), in-place over h ----------------
__global__ __launch_bounds__(256) void cd2_kernel(
    const float* h_in, const float* __restrict__ cd2_w,
    const float* __restrict__ cd2_b, float* cs_out, int N)
{
    __shared__ float Wt[64 * D];
    __shared__ float Cn[TM * CSTR];
    int t = threadIdx.x;
    int n0 = blockIdx.x * TM;
    int cg = t & 31, ng = t >> 5;
    int c0 = cg * 4;
    float4 acc[8];
    #pragma unroll
    for (int jj = 0; jj < 8; jj++) acc[jj] = make_float4(0.f, 0.f, 0.f, 0.f);

    for (int kt = 0; kt < 2; kt++) {
        int k0 = kt * 64;
        __syncthreads();
        const float4* Wg = (const float4*)(cd2_w + (size_t)k0 * D);
        float4* Wl = (float4*)Wt;
        #pragma unroll
        for (int i = 0; i < 8; i++) Wl[i * 256 + t] = Wg[i * 256 + t];
        #pragma unroll
        for (int i = 0; i < 4; i++) {
            int f = i * 256 + t;
            int n = f >> 4, k4 = f & 15;
            int nn = n0 + n; if (nn >= N) nn = N - 1;
            float4 v = *(const float4*)&h_in[(size_t)nn * D + k0 + k4 * 4];
            *(float4*)&Cn[n * CSTR + k4 * 4] = v;
        }
        __syncthreads();
        #pragma unroll 4
        for (int k4 = 0; k4 < 16; k4++) {
            float4 w0 = *(float4*)&Wt[(k4 * 4 + 0) * D + c0];
            float4 w1 = *(float4*)&Wt[(k4 * 4 + 1) * D + c0];
            float4 w2 = *(float4*)&Wt[(k4 * 4 + 2) * D + c0];
            float4 w3 = *(float4*)&Wt[(k4 * 4 + 3) * D + c0];
            #pragma unroll
            for (int jj = 0; jj < 8; jj++) {
                float4 cv = *(float4*)&Cn[(ng * 8 + jj) * CSTR + k4 * 4];
                fma4(acc[jj], cv, w0, w1, w2, w3);
            }
        }
    }
    float4 b = *(const float4*)&cd2_b[c0];
    #pragma unroll
    for (int jj = 0; jj < 8; jj++) {
        int n = n0 + ng * 8 + jj;
        if (n < N) {
            float4 r;
            r.x = 1.f / (1.f + __expf(-(acc[jj].x + b.x)));
            r.y = 1.f / (1.f + __expf(-(acc[jj].y + b.y)));
            r.z = 1.f / (1.f + __expf(-(acc[jj].z + b.z)));
            r.w = 1.f / (1.f + __expf(-(acc[jj].w + b.w)));
            *(float4*)&cs_out[(size_t)n * D + c0] = r;
        }
    }
}

// ---------------- Kernel 3c: final = node_px + cs * ((node_px+agg) @ int_w + int_b) ----------------
// final_x written over node_px (same buffer): block-local read-before-write, safe.
__global__ __launch_bounds__(256) void final_kernel(
    const float* node_px, const float* __restrict__ agg,
    const float* __restrict__ cs, const float* __restrict__ int_w,
    const float* __restrict__ int_b, float* final_x, int N)
{
    __shared__ float Wt[64 * D];
    __shared__ float Cn[TM * CSTR];
    int t = threadIdx.x;
    int n0 = blockIdx.x * TM;
    int cg = t & 31, ng = t >> 5;
    int c0 = cg * 4;
    float4 acc[8];
    #pragma unroll
    for (int jj = 0; jj < 8; jj++) acc[jj] = make_float4(0.f, 0.f, 0.f, 0.f);

    for (int kt = 0; kt < 2; kt++) {
        int k0 = kt * 64;
        __syncthreads();
        const float4* Wg = (const float4*)(int_w + (size_t)k0 * D);
        float4* Wl = (float4*)Wt;
        #pragma unroll
        for (int i = 0; i < 8; i++) Wl[i * 256 + t] = Wg[i * 256 + t];
        #pragma unroll
        for (int i = 0; i < 4; i++) {
            int f = i * 256 + t;
            int n = f >> 4, k4 = f & 15;
            int nn = n0 + n; if (nn >= N) nn = N - 1;
            float4 a4 = *(const float4*)&node_px[(size_t)nn * D + k0 + k4 * 4];
            float4 b4 = *(const float4*)&agg[(size_t)nn * D + k0 + k4 * 4];
            float4 v = make_float4(a4.x + b4.x, a4.y + b4.y, a4.z + b4.z, a4.w + b4.w);
            *(float4*)&Cn[n * CSTR + k4 * 4] = v;
        }
        __syncthreads();
        #pragma unroll 4
        for (int k4 = 0; k4 < 16; k4++) {
            float4 w0 = *(float4*)&Wt[(k4 * 4 + 0) * D + c0];
            float4 w1 = *(float4*)&Wt[(k4 * 4 + 1) * D + c0];
            float4 w2 = *(float4*)&Wt[(k4 * 4 + 2) * D + c0];
            float4 w3 = *(float4*)&Wt[(k4 * 4 + 3) * D + c0];
            #pragma unroll
            for (int jj = 0; jj < 8; jj++) {
                float4 cv = *(float4*)&Cn[(ng * 8 + jj) * CSTR + k4 * 4];
                fma4(acc[jj], cv, w0, w1, w2, w3);
            }
        }
    }
    float4 b = *(const float4*)&int_b[c0];
    #pragma unroll
    for (int jj = 0; jj < 8; jj++) {
        int n = n0 + ng * 8 + jj;
        if (n < N) {
            float4 iv = make_float4(acc[jj].x + b.x, acc[jj].y + b.y,
                                    acc[jj].z + b.z, acc[jj].w + b.w);
            float4 c4 = *(const float4*)&cs[(size_t)n * D + c0];
            float4 np = *(const float4*)&node_px[(size_t)n * D + c0];
            float4 r;
            r.x = np.x + c4.x * iv.x;
            r.y = np.y + c4.y * iv.y;
            r.z = np.z + c4.z * iv.z;
            r.w = np.w + c4.w * iv.w;
            *(float4*)&final_x[(size_t)n * D + c0] = r;
        }
    }
}

extern "C" void kernel_launch(void* const* d_in, const int* in_sizes, int n_in,
                              void* d_out, int out_size, void* d_ws, size_t ws_size,
                              hipStream_t stream)
{
    const float* x           = (const float*)d_in[0];
    const float* anchor_node = (const float*)d_in[1];
    const float* attn_w      = (const float*)d_in[2];
    const float* attn_b      = (const float*)d_in[3];
    const float* anchor_edge = (const float*)d_in[4];
    const float* w_w         = (const float*)d_in[5];
    const float* w_b         = (const float*)d_in[6];
    const float* cd1_w       = (const float*)d_in[7];
    const float* cd1_b       = (const float*)d_in[8];
    const float* cd2_w       = (const float*)d_in[9];
    const float* cd2_b       = (const float*)d_in[10];
    const float* int_w       = (const float*)d_in[11];
    const float* int_b       = (const float*)d_in[12];
    const int*   ei          = (const int*)d_in[13];

    int N = in_sizes[0] / D;
    int E = in_sizes[13] / 2;

    float* out         = (float*)d_out;
    float* node_px     = out;                       // reuse final_x slot for node_px
    float* edge_prompt = out + (size_t)N * D;
    float* agg         = (float*)d_ws;              // N*D floats
    float* h           = agg + (size_t)N * D;       // N*D floats (h, then cs in-place)
    // bagg/lsrc/ldst live inside the h region (15*N floats << N*D floats);
    // all three are dead before cd1 writes h.
    float* bagg        = h;                         // N*A floats
    float* lsrc        = h + (size_t)N * A;         // N*A floats
    float* ldst        = h + (size_t)2 * N * A;     // N*A floats

    // only the tiny coefficient accumulator needs zeroing (1 MB)
    hipMemsetAsync(bagg, 0, (size_t)N * A * sizeof(float), stream);

    node_prompt_kernel<<<512, 256, 0, stream>>>(x, attn_w, attn_b, anchor_node, w_w,
                                                node_px, lsrc, ldst, N);
    int nb_e = (E + 255) / 256;
    edge_kernel<<<nb_e, 256, 0, stream>>>(ei, lsrc, ldst, w_b, anchor_edge,
                                          edge_prompt, bagg, E);
    agg_kernel<<<2048, 256, 0, stream>>>(bagg, anchor_edge, agg, N);

    int nb = (N + TM - 1) / TM;
    cd1_kernel<<<nb, 256, 0, stream>>>(node_px, agg, cd1_w, cd1_b, h, N);
    cd2_kernel<<<nb, 256, 0, stream>>>(h, cd2_w, cd2_b, h, N);
    final_kernel<<<nb, 256, 0, stream>>>(node_px, agg, h, int_w, int_b, node_px, N);
}

// Round 3
// 804.792 us; speedup vs baseline: 1.2627x; 1.2627x over previous
//
#include <hip/hip_runtime.h>
#include <math.h>

#define D 128
#define A 5
#define TM 64
#define CSTR 68   // padded LDS stride for 64-wide combined tile (68*4B = 272B, 16B-aligned rows)

// ---------------- Kernel 1: node prompt + per-node edge-logit tables ----------------
// node_px = x + softmax(x@attn_w + attn_b) @ anchor_node, plus the rank-factored
// edge logit tables lsrc = x @ w_w[0:D], ldst = x @ w_w[D:2D].
__global__ __launch_bounds__(256) void node_prompt_kernel(
    const float* __restrict__ x,
    const float* __restrict__ attn_w, const float* __restrict__ attn_b,
    const float* __restrict__ anchor_node,
    const float* __restrict__ w_w,
    float* __restrict__ node_px,
    float* __restrict__ lsrc, float* __restrict__ ldst, int N)
{
    int t = threadIdx.x;
    int lane = t & 63;
    int j = lane * 2;
    float At0[A], At1[A], AN0[A], AN1[A], Ab[A];
    float W0[A], W1[A], W2[A], W3[A];
    #pragma unroll
    for (int a = 0; a < A; a++) {
        At0[a] = attn_w[(size_t)j * A + a];
        At1[a] = attn_w[(size_t)(j + 1) * A + a];
        AN0[a] = anchor_node[a * D + j];
        AN1[a] = anchor_node[a * D + j + 1];
        Ab[a]  = attn_b[a];
        W0[a]  = w_w[(size_t)j * A + a];
        W1[a]  = w_w[(size_t)(j + 1) * A + a];
        W2[a]  = w_w[(size_t)(D + j) * A + a];
        W3[a]  = w_w[(size_t)(D + j + 1) * A + a];
    }
    int wid = blockIdx.x * 4 + (t >> 6);
    int nw  = gridDim.x * 4;
    for (int n = wid; n < N; n += nw) {
        float2 xv = *(const float2*)&x[(size_t)n * D + j];
        float l[A], es[A], ed[A];
        #pragma unroll
        for (int a = 0; a < A; a++) {
            float p0 = xv.x * At0[a] + xv.y * At1[a];
            float p1 = xv.x * W0[a]  + xv.y * W1[a];
            float p2 = xv.x * W2[a]  + xv.y * W3[a];
            #pragma unroll
            for (int off = 32; off; off >>= 1) {
                p0 += __shfl_xor(p0, off);
                p1 += __shfl_xor(p1, off);
                p2 += __shfl_xor(p2, off);
            }
            l[a]  = p0 + Ab[a];
            es[a] = p1;
            ed[a] = p2;
        }
        float m = l[0];
        #pragma unroll
        for (int a = 1; a < A; a++) m = fmaxf(m, l[a]);
        float s = 0.f;
        #pragma unroll
        for (int a = 0; a < A; a++) { l[a] = __expf(l[a] - m); s += l[a]; }
        float inv = 1.f / s;
        float2 o = xv;
        #pragma unroll
        for (int a = 0; a < A; a++) {
            float w = l[a] * inv;
            o.x += w * AN0[a];
            o.y += w * AN1[a];
        }
        *(float2*)&node_px[(size_t)n * D + j] = o;
        if (lane < A) {
            float vs = es[0], vd = ed[0];
            #pragma unroll
            for (int a = 1; a < A; a++) if (lane == a) { vs = es[a]; vd = ed[a]; }
            lsrc[(size_t)n * A + lane] = vs;
            ldst[(size_t)n * A + lane] = vd;
        }
    }
}

// ---------------- Kernel 2: edge softmax from tables, wave-per-edge ----------------
// One WAVE per edge: s,d are wave-uniform -> table reads are scalar/broadcast
// loads; softmax computed redundantly in-register in every lane (no shuffles);
// each lane writes its 2 edge_prompt columns (512B coalesced store per wave);
// coefficient atomics issued from lanes 0..4 (row s) and 32..36 (row d) so each
// atomic instruction touches only 2 cache lines (round-2's thread-per-edge
// version hit 64 random lines per instruction -> +240MB HBM write overhead).
__global__ __launch_bounds__(256) void edge_kernel(
    const int* __restrict__ ei,
    const float* __restrict__ lsrc, const float* __restrict__ ldst,
    const float* __restrict__ w_b, const float* __restrict__ anchor_edge,
    float* __restrict__ edge_prompt, float* __restrict__ bagg, int E)
{
    int t = threadIdx.x;
    int lane = t & 63;
    int j = lane * 2;
    float AE0[A], AE1[A], Wb[A];
    #pragma unroll
    for (int a = 0; a < A; a++) {
        AE0[a] = anchor_edge[a * D + j];
        AE1[a] = anchor_edge[a * D + j + 1];
        Wb[a]  = w_b[a];
    }
    int sub  = lane & 31;
    int half = lane >> 5;
    int wid = blockIdx.x * 4 + (t >> 6);
    int nw  = gridDim.x * 4;
    #pragma unroll 2
    for (int e = wid; e < E; e += nw) {
        int s = __builtin_amdgcn_readfirstlane(ei[e]);
        int d = __builtin_amdgcn_readfirstlane(ei[(size_t)E + e]);
        const float* ps = &lsrc[(size_t)s * A];
        const float* pd = &ldst[(size_t)d * A];
        float l[A];
        #pragma unroll
        for (int a = 0; a < A; a++) {
            float p = ps[a] + pd[a] + Wb[a];
            l[a] = (p > 0.f) ? p : 0.01f * p;   // leaky_relu (slope 0.01)
        }
        float m = l[0];
        #pragma unroll
        for (int a = 1; a < A; a++) m = fmaxf(m, l[a]);
        float sum = 0.f;
        #pragma unroll
        for (int a = 0; a < A; a++) { l[a] = __expf(l[a] - m); sum += l[a]; }
        float inv = 1.f / sum;
        float2 ep = make_float2(0.f, 0.f);
        #pragma unroll
        for (int a = 0; a < A; a++) {
            float b = l[a] * inv;
            ep.x += b * AE0[a];
            ep.y += b * AE1[a];
        }
        *(float2*)&edge_prompt[(size_t)e * D + j] = ep;
        if (sub < A) {
            float bv = l[0];
            #pragma unroll
            for (int a = 1; a < A; a++) if (sub == a) bv = l[a];
            bv *= inv;
            int node = half ? d : s;
            atomicAdd(&bagg[(size_t)node * A + sub], bv);
        }
    }
}

// ---------------- Kernel 2b: agg = bagg @ anchor_edge  (N x A x D, tiny) ----------------
__global__ __launch_bounds__(256) void agg_kernel(
    const float* __restrict__ bagg, const float* __restrict__ anchor_edge,
    float* __restrict__ agg, int N)
{
    __shared__ float AE[A * D];
    int t = threadIdx.x;
    for (int f = t; f < A * D; f += 256) AE[f] = anchor_edge[f];
    __syncthreads();
    int total = N * (D / 4);   // float4 chunks
    for (int i = blockIdx.x * 256 + t; i < total; i += gridDim.x * 256) {
        int n = i >> 5;
        int c = (i & 31) * 4;
        const float* br = &bagg[(size_t)n * A];
        float b0 = br[0], b1 = br[1], b2 = br[2], b3 = br[3], b4 = br[4];
        float4 e0 = *(float4*)&AE[0 * D + c];
        float4 e1 = *(float4*)&AE[1 * D + c];
        float4 e2 = *(float4*)&AE[2 * D + c];
        float4 e3 = *(float4*)&AE[3 * D + c];
        float4 e4 = *(float4*)&AE[4 * D + c];
        float4 r;
        r.x = b0 * e0.x + b1 * e1.x + b2 * e2.x + b3 * e3.x + b4 * e4.x;
        r.y = b0 * e0.y + b1 * e1.y + b2 * e2.y + b3 * e3.y + b4 * e4.y;
        r.z = b0 * e0.z + b1 * e1.z + b2 * e2.z + b3 * e3.z + b4 * e4.z;
        r.w = b0 * e0.w + b1 * e1.w + b2 * e2.w + b3 * e3.w + b4 * e4.w;
        *(float4*)&agg[(size_t)n * D + c] = r;
    }
}

// ---------------- helper: 4x4 outer-product FMA ----------------
__device__ __forceinline__ void fma4(float4& acc, const float4 cv,
                                     const float4 w0, const float4 w1,
                                     const float4 w2, const float4 w3)
{
    acc.x += cv.x * w0.x + cv.y * w1.x + cv.z * w2.x + cv.w * w3.x;
    acc.y += cv.x * w0.y + cv.y * w1.y + cv.z * w2.y + cv.w * w3.y;
    acc.z += cv.x * w0.z + cv.y * w1.z + cv.z * w2.z + cv.w * w3.z;
    acc.w += cv.x * w0.w + cv.y * w1.w + cv.z * w2.w + cv.w * w3.w;
}

// ---------------- Kernel 3a: h = relu([node_px, agg] @ cd1_w + cd1_b) ----------------
__global__ __launch_bounds__(256) void cd1_kernel(
    const float* __restrict__ node_px, const float* __restrict__ agg,
    const float* __restrict__ cd1_w, const float* __restrict__ cd1_b,
    float* __restrict__ h, int N)
{
    __shared__ float Wt[64 * D];       // 32 KB
    __shared__ float Cn[TM * CSTR];    // 17.4 KB
    int t = threadIdx.x;
    int n0 = blockIdx.x * TM;
    int cg = t & 31, ng = t >> 5;
    int c0 = cg * 4;
    float4 acc[8];
    #pragma unroll
    for (int jj = 0; jj < 8; jj++) acc[jj] = make_float4(0.f, 0.f, 0.f, 0.f);

    for (int kt = 0; kt < 4; kt++) {
        int k0 = kt * 64;
        __syncthreads();
        const float4* Wg = (const float4*)(cd1_w + (size_t)k0 * D);
        float4* Wl = (float4*)Wt;
        #pragma unroll
        for (int i = 0; i < 8; i++) Wl[i * 256 + t] = Wg[i * 256 + t];
        const float* src = (k0 < 128) ? node_px : agg;
        int koff = k0 & 127;
        #pragma unroll
        for (int i = 0; i < 4; i++) {
            int f = i * 256 + t;
            int n = f >> 4, k4 = f & 15;
            int nn = n0 + n; if (nn >= N) nn = N - 1;
            float4 v = *(const float4*)&src[(size_t)nn * D + koff + k4 * 4];
            *(float4*)&Cn[n * CSTR + k4 * 4] = v;
        }
        __syncthreads();
        #pragma unroll 4
        for (int k4 = 0; k4 < 16; k4++) {
            float4 w0 = *(float4*)&Wt[(k4 * 4 + 0) * D + c0];
            float4 w1 = *(float4*)&Wt[(k4 * 4 + 1) * D + c0];
            float4 w2 = *(float4*)&Wt[(k4 * 4 + 2) * D + c0];
            float4 w3 = *(float4*)&Wt[(k4 * 4 + 3) * D + c0];
            #pragma unroll
            for (int jj = 0; jj < 8; jj++) {
                float4 cv = *(float4*)&Cn[(ng * 8 + jj) * CSTR + k4 * 4];
                fma4(acc[jj], cv, w0, w1, w2, w3);
            }
        }
    }
    float4 b = *(const float4*)&cd1_b[c0];
    #pragma unroll
    for (int jj = 0; jj < 8; jj++) {
        int n = n0 + ng * 8 + jj;
        if (n < N) {
            float4 r;
            r.x = fmaxf(acc[jj].x + b.x, 0.f);
            r.y = fmaxf(acc[jj].y + b.y, 0.f);
            r.z = fmaxf(acc[jj].z + b.z, 0.f);
            r.w = fmaxf(acc[jj].w + b.w, 0.f);
            *(float4*)&h[(size_t)n * D + c0] = r;
        }
    }
}

// ---------------- Kernel 3b: cs = sigmoid(h @ cd2_w + cd2_b), in-place over h ----------------
__global__ __launch_bounds__(256) void cd2_kernel(
    const float* h_in, const float* __restrict__ cd2_w,
    const float* __restrict__ cd2_b, float* cs_out, int N)
{
    __shared__ float Wt[64 * D];
    __shared__ float Cn[TM * CSTR];
    int t = threadIdx.x;
    int n0 = blockIdx.x * TM;
    int cg = t & 31, ng = t >> 5;
    int c0 = cg * 4;
    float4 acc[8];
    #pragma unroll
    for (int jj = 0; jj < 8; jj++) acc[jj] = make_float4(0.f, 0.f, 0.f, 0.f);

    for (int kt = 0; kt < 2; kt++) {
        int k0 = kt * 64;
        __syncthreads();
        const float4* Wg = (const float4*)(cd2_w + (size_t)k0 * D);
        float4* Wl = (float4*)Wt;
        #pragma unroll
        for (int i = 0; i < 8; i++) Wl[i * 256 + t] = Wg[i * 256 + t];
        #pragma unroll
        for (int i = 0; i < 4; i++) {
            int f = i * 256 + t;
            int n = f >> 4, k4 = f & 15;
            int nn = n0 + n; if (nn >= N) nn = N - 1;
            float4 v = *(const float4*)&h_in[(size_t)nn * D + k0 + k4 * 4];
            *(float4*)&Cn[n * CSTR + k4 * 4] = v;
        }
        __syncthreads();
        #pragma unroll 4
        for (int k4 = 0; k4 < 16; k4++) {
            float4 w0 = *(float4*)&Wt[(k4 * 4 + 0) * D + c0];
            float4 w1 = *(float4*)&Wt[(k4 * 4 + 1) * D + c0];
            float4 w2 = *(float4*)&Wt[(k4 * 4 + 2) * D + c0];
            float4 w3 = *(float4*)&Wt[(k4 * 4 + 3) * D + c0];
            #pragma unroll
            for (int jj = 0; jj < 8; jj++) {
                float4 cv = *(float4*)&Cn[(ng * 8 + jj) * CSTR + k4 * 4];
                fma4(acc[jj], cv, w0, w1, w2, w3);
            }
        }
    }
    float4 b = *(const float4*)&cd2_b[c0];
    #pragma unroll
    for (int jj = 0; jj < 8; jj++) {
        int n = n0 + ng * 8 + jj;
        if (n < N) {
            float4 r;
            r.x = 1.f / (1.f + __expf(-(acc[jj].x + b.x)));
            r.y = 1.f / (1.f + __expf(-(acc[jj].y + b.y)));
            r.z = 1.f / (1.f + __expf(-(acc[jj].z + b.z)));
            r.w = 1.f / (1.f + __expf(-(acc[jj].w + b.w)));
            *(float4*)&cs_out[(size_t)n * D + c0] = r;
        }
    }
}

// ---------------- Kernel 3c: final = node_px + cs * ((node_px+agg) @ int_w + int_b) ----------------
__global__ __launch_bounds__(256) void final_kernel(
    const float* node_px, const float* __restrict__ agg,
    const float* __restrict__ cs, const float* __restrict__ int_w,
    const float* __restrict__ int_b, float* final_x, int N)
{
    __shared__ float Wt[64 * D];
    __shared__ float Cn[TM * CSTR];
    int t = threadIdx.x;
    int n0 = blockIdx.x * TM;
    int cg = t & 31, ng = t >> 5;
    int c0 = cg * 4;
    float4 acc[8];
    #pragma unroll
    for (int jj = 0; jj < 8; jj++) acc[jj] = make_float4(0.f, 0.f, 0.f, 0.f);

    for (int kt = 0; kt < 2; kt++) {
        int k0 = kt * 64;
        __syncthreads();
        const float4* Wg = (const float4*)(int_w + (size_t)k0 * D);
        float4* Wl = (float4*)Wt;
        #pragma unroll
        for (int i = 0; i < 8; i++) Wl[i * 256 + t] = Wg[i * 256 + t];
        #pragma unroll
        for (int i = 0; i < 4; i++) {
            int f = i * 256 + t;
            int n = f >> 4, k4 = f & 15;
            int nn = n0 + n; if (nn >= N) nn = N - 1;
            float4 a4 = *(const float4*)&node_px[(size_t)nn * D + k0 + k4 * 4];
            float4 b4 = *(const float4*)&agg[(size_t)nn * D + k0 + k4 * 4];
            float4 v = make_float4(a4.x + b4.x, a4.y + b4.y, a4.z + b4.z, a4.w + b4.w);
            *(float4*)&Cn[n * CSTR + k4 * 4] = v;
        }
        __syncthreads();
        #pragma unroll 4
        for (int k4 = 0; k4 < 16; k4++) {
            float4 w0 = *(float4*)&Wt[(k4 * 4 + 0) * D + c0];
            float4 w1 = *(float4*)&Wt[(k4 * 4 + 1) * D + c0];
            float4 w2 = *(float4*)&Wt[(k4 * 4 + 2) * D + c0];
            float4 w3 = *(float4*)&Wt[(k4 * 4 + 3) * D + c0];
            #pragma unroll
            for (int jj = 0; jj < 8; jj++) {
                float4 cv = *(float4*)&Cn[(ng * 8 + jj) * CSTR + k4 * 4];
                fma4(acc[jj], cv, w0, w1, w2, w3);
            }
        }
    }
    float4 b = *(const float4*)&int_b[c0];
    #pragma unroll
    for (int jj = 0; jj < 8; jj++) {
        int n = n0 + ng * 8 + jj;
        if (n < N) {
            float4 iv = make_float4(acc[jj].x + b.x, acc[jj].y + b.y,
                                    acc[jj].z + b.z, acc[jj].w + b.w);
            float4 c4 = *(const float4*)&cs[(size_t)n * D + c0];
            float4 np = *(const float4*)&node_px[(size_t)n * D + c0];
            float4 r;
            r.x = np.x + c4.x * iv.x;
            r.y = np.y + c4.y * iv.y;
            r.z = np.z + c4.z * iv.z;
            r.w = np.w + c4.w * iv.w;
            *(float4*)&final_x[(size_t)n * D + c0] = r;
        }
    }
}

extern "C" void kernel_launch(void* const* d_in, const int* in_sizes, int n_in,
                              void* d_out, int out_size, void* d_ws, size_t ws_size,
                              hipStream_t stream)
{
    const float* x           = (const float*)d_in[0];
    const float* anchor_node = (const float*)d_in[1];
    const float* attn_w      = (const float*)d_in[2];
    const float* attn_b      = (const float*)d_in[3];
    const float* anchor_edge = (const float*)d_in[4];
    const float* w_w         = (const float*)d_in[5];
    const float* w_b         = (const float*)d_in[6];
    const float* cd1_w       = (const float*)d_in[7];
    const float* cd1_b       = (const float*)d_in[8];
    const float* cd2_w       = (const float*)d_in[9];
    const float* cd2_b       = (const float*)d_in[10];
    const float* int_w       = (const float*)d_in[11];
    const float* int_b       = (const float*)d_in[12];
    const int*   ei          = (const int*)d_in[13];

    int N = in_sizes[0] / D;
    int E = in_sizes[13] / 2;

    float* out         = (float*)d_out;
    float* node_px     = out;                       // reuse final_x slot for node_px
    float* edge_prompt = out + (size_t)N * D;
    float* agg         = (float*)d_ws;              // N*D floats
    float* h           = agg + (size_t)N * D;       // N*D floats (h, then cs in-place)
    // bagg/lsrc/ldst live inside the h region (15*N floats << N*D floats);
    // all three are dead before cd1 writes h.
    float* bagg        = h;                         // N*A floats
    float* lsrc        = h + (size_t)N * A;         // N*A floats
    float* ldst        = h + (size_t)2 * N * A;     // N*A floats

    hipMemsetAsync(bagg, 0, (size_t)N * A * sizeof(float), stream);

    node_prompt_kernel<<<512, 256, 0, stream>>>(x, attn_w, attn_b, anchor_node, w_w,
                                                node_px, lsrc, ldst, N);
    edge_kernel<<<2048, 256, 0, stream>>>(ei, lsrc, ldst, w_b, anchor_edge,
                                          edge_prompt, bagg, E);
    agg_kernel<<<2048, 256, 0, stream>>>(bagg, anchor_edge, agg, N);

    int nb = (N + TM - 1) / TM;
    cd1_kernel<<<nb, 256, 0, stream>>>(node_px, agg, cd1_w, cd1_b, h, N);
    cd2_kernel<<<nb, 256, 0, stream>>>(h, cd2_w, cd2_b, h, N);
    final_kernel<<<nb, 256, 0, stream>>>(node_px, agg, h, int_w, int_b, node_px, N);
}

// Round 4
// 789.098 us; speedup vs baseline: 1.2878x; 1.0199x over previous
//
#include <hip/hip_runtime.h>
#include <math.h>

#define D 128
#define A 5
#define TM 64

// ---------------- Kernel 1: node prompt + per-node edge-logit tables ----------------
// node_px = x + softmax(x@attn_w + attn_b) @ anchor_node, plus the rank-factored
// edge logit tables lsrc = x @ w_w[0:D], ldst = x @ w_w[D:2D].
__global__ __launch_bounds__(256) void node_prompt_kernel(
    const float* __restrict__ x,
    const float* __restrict__ attn_w, const float* __restrict__ attn_b,
    const float* __restrict__ anchor_node,
    const float* __restrict__ w_w,
    float* __restrict__ node_px,
    float* __restrict__ lsrc, float* __restrict__ ldst, int N)
{
    int t = threadIdx.x;
    int lane = t & 63;
    int j = lane * 2;
    float At0[A], At1[A], AN0[A], AN1[A], Ab[A];
    float W0[A], W1[A], W2[A], W3[A];
    #pragma unroll
    for (int a = 0; a < A; a++) {
        At0[a] = attn_w[(size_t)j * A + a];
        At1[a] = attn_w[(size_t)(j + 1) * A + a];
        AN0[a] = anchor_node[a * D + j];
        AN1[a] = anchor_node[a * D + j + 1];
        Ab[a]  = attn_b[a];
        W0[a]  = w_w[(size_t)j * A + a];
        W1[a]  = w_w[(size_t)(j + 1) * A + a];
        W2[a]  = w_w[(size_t)(D + j) * A + a];
        W3[a]  = w_w[(size_t)(D + j + 1) * A + a];
    }
    int wid = blockIdx.x * 4 + (t >> 6);
    int nw  = gridDim.x * 4;
    for (int n = wid; n < N; n += nw) {
        float2 xv = *(const float2*)&x[(size_t)n * D + j];
        float l[A], es[A], ed[A];
        #pragma unroll
        for (int a = 0; a < A; a++) {
            float p0 = xv.x * At0[a] + xv.y * At1[a];
            float p1 = xv.x * W0[a]  + xv.y * W1[a];
            float p2 = xv.x * W2[a]  + xv.y * W3[a];
            #pragma unroll
            for (int off = 32; off; off >>= 1) {
                p0 += __shfl_xor(p0, off);
                p1 += __shfl_xor(p1, off);
                p2 += __shfl_xor(p2, off);
            }
            l[a]  = p0 + Ab[a];
            es[a] = p1;
            ed[a] = p2;
        }
        float m = l[0];
        #pragma unroll
        for (int a = 1; a < A; a++) m = fmaxf(m, l[a]);
        float s = 0.f;
        #pragma unroll
        for (int a = 0; a < A; a++) { l[a] = __expf(l[a] - m); s += l[a]; }
        float inv = 1.f / s;
        float2 o = xv;
        #pragma unroll
        for (int a = 0; a < A; a++) {
            float w = l[a] * inv;
            o.x += w * AN0[a];
            o.y += w * AN1[a];
        }
        *(float2*)&node_px[(size_t)n * D + j] = o;
        if (lane < A) {
            float vs = es[0], vd = ed[0];
            #pragma unroll
            for (int a = 1; a < A; a++) if (lane == a) { vs = es[a]; vd = ed[a]; }
            lsrc[(size_t)n * A + lane] = vs;
            ldst[(size_t)n * A + lane] = vd;
        }
    }
}

// ---------------- Kernel 2: edge softmax from tables, wave-per-edge ----------------
// One WAVE per edge: s,d wave-uniform -> scalar/broadcast table reads, softmax
// redundantly in-register (no shuffles), 512B coalesced edge_prompt store per
// wave, coefficient atomics from 10 lanes hitting only 2 cache lines.
__global__ __launch_bounds__(256) void edge_kernel(
    const int* __restrict__ ei,
    const float* __restrict__ lsrc, const float* __restrict__ ldst,
    const float* __restrict__ w_b, const float* __restrict__ anchor_edge,
    float* __restrict__ edge_prompt, float* __restrict__ bagg, int E)
{
    int t = threadIdx.x;
    int lane = t & 63;
    int j = lane * 2;
    float AE0[A], AE1[A], Wb[A];
    #pragma unroll
    for (int a = 0; a < A; a++) {
        AE0[a] = anchor_edge[a * D + j];
        AE1[a] = anchor_edge[a * D + j + 1];
        Wb[a]  = w_b[a];
    }
    int sub  = lane & 31;
    int half = lane >> 5;
    int wid = blockIdx.x * 4 + (t >> 6);
    int nw  = gridDim.x * 4;
    #pragma unroll 2
    for (int e = wid; e < E; e += nw) {
        int s = __builtin_amdgcn_readfirstlane(ei[e]);
        int d = __builtin_amdgcn_readfirstlane(ei[(size_t)E + e]);
        const float* ps = &lsrc[(size_t)s * A];
        const float* pd = &ldst[(size_t)d * A];
        float l[A];
        #pragma unroll
        for (int a = 0; a < A; a++) {
            float p = ps[a] + pd[a] + Wb[a];
            l[a] = (p > 0.f) ? p : 0.01f * p;   // leaky_relu (slope 0.01)
        }
        float m = l[0];
        #pragma unroll
        for (int a = 1; a < A; a++) m = fmaxf(m, l[a]);
        float sum = 0.f;
        #pragma unroll
        for (int a = 0; a < A; a++) { l[a] = __expf(l[a] - m); sum += l[a]; }
        float inv = 1.f / sum;
        float2 ep = make_float2(0.f, 0.f);
        #pragma unroll
        for (int a = 0; a < A; a++) {
            float b = l[a] * inv;
            ep.x += b * AE0[a];
            ep.y += b * AE1[a];
        }
        *(float2*)&edge_prompt[(size_t)e * D + j] = ep;
        if (sub < A) {
            float bv = l[0];
            #pragma unroll
            for (int a = 1; a < A; a++) if (sub == a) bv = l[a];
            bv *= inv;
            int node = half ? d : s;
            atomicAdd(&bagg[(size_t)node * A + sub], bv);
        }
    }
}

// ---------------- helper: 4x4 outer-product FMA ----------------
__device__ __forceinline__ void fma4(float4& acc, const float4 cv,
                                     const float4 w0, const float4 w1,
                                     const float4 w2, const float4 w3)
{
    acc.x += cv.x * w0.x + cv.y * w1.x + cv.z * w2.x + cv.w * w3.x;
    acc.y += cv.x * w0.y + cv.y * w1.y + cv.z * w2.y + cv.w * w3.y;
    acc.z += cv.x * w0.z + cv.y * w1.z + cv.z * w2.z + cv.w * w3.z;
    acc.w += cv.x * w0.w + cv.y * w1.w + cv.z * w2.w + cv.w * w3.w;
}

__device__ __forceinline__ float4 agg_otf(const float* __restrict__ br,
                                          const float4* AEh)
{
    // one float4 of agg row: sum_a bagg[a] * AE[a][cols]
    float b0 = br[0], b1 = br[1], b2 = br[2], b3 = br[3], b4 = br[4];
    float4 v;
    v.x = b0*AEh[0].x + b1*AEh[1].x + b2*AEh[2].x + b3*AEh[3].x + b4*AEh[4].x;
    v.y = b0*AEh[0].y + b1*AEh[1].y + b2*AEh[2].y + b3*AEh[3].y + b4*AEh[4].y;
    v.z = b0*AEh[0].z + b1*AEh[1].z + b2*AEh[2].z + b3*AEh[3].z + b4*AEh[4].z;
    v.w = b0*AEh[0].w + b1*AEh[1].w + b2*AEh[2].w + b3*AEh[3].w + b4*AEh[4].w;
    return v;
}

// ---------------- Kernel 3: FUSED cd1 -> cd2 -> final, one pass per 64-row tile ----
// h lives in LDS (Buf), cs lives in registers (same thread owns the same
// (row,col) positions across all three GEMMs). agg is NEVER materialized:
// each staged float4 of it is bagg[n] (20B, L2-hot) dotted with 5 fixed AE
// columns held in registers (k4 = t&15 is constant per thread since 256%16==0).
__global__ __launch_bounds__(256) void fused_tail_kernel(
    const float* __restrict__ node_px, const float* __restrict__ bagg,
    const float* __restrict__ anchor_edge,
    const float* __restrict__ cd1_w, const float* __restrict__ cd1_b,
    const float* __restrict__ cd2_w, const float* __restrict__ cd2_b,
    const float* __restrict__ int_w, const float* __restrict__ int_b,
    float* __restrict__ final_x, int N)
{
    __shared__ float Wt[64 * D];    // 32 KB weight tile (restaged per k-tile)
    __shared__ float Buf[TM * D];   // 32 KB: operand slices (cols 0-63), then h
    int t = threadIdx.x;
    int n0 = blockIdx.x * TM;
    int cg = t & 31, ng = t >> 5;
    int c0 = cg * 4;
    int k4s = t & 15;               // fixed staging column sub-index

    // AE columns needed for on-the-fly agg staging: [koff half][anchor]
    float4 AEr[2][A];
    #pragma unroll
    for (int hh = 0; hh < 2; hh++)
        #pragma unroll
        for (int a = 0; a < A; a++)
            AEr[hh][a] = *(const float4*)&anchor_edge[a * D + hh * 64 + k4s * 4];

    float4 acc[8];
    #pragma unroll
    for (int jj = 0; jj < 8; jj++) acc[jj] = make_float4(0.f, 0.f, 0.f, 0.f);

    // ---- GEMM1: combined[64][256] @ cd1_w ----
    for (int kt = 0; kt < 4; kt++) {
        int k0 = kt * 64;
        __syncthreads();
        const float4* Wg = (const float4*)(cd1_w + (size_t)k0 * D);
        float4* Wl = (float4*)Wt;
        #pragma unroll
        for (int i = 0; i < 8; i++) Wl[i * 256 + t] = Wg[i * 256 + t];
        #pragma unroll
        for (int i = 0; i < 4; i++) {
            int f = i * 256 + t;
            int n = f >> 4;
            int nn = n0 + n; if (nn >= N) nn = N - 1;
            float4 v;
            if (kt < 2) {
                v = *(const float4*)&node_px[(size_t)nn * D + k0 + k4s * 4];
            } else {
                v = agg_otf(&bagg[(size_t)nn * A], AEr[kt - 2]);
            }
            *(float4*)&Buf[n * D + k4s * 4] = v;
        }
        __syncthreads();
        #pragma unroll 4
        for (int k4 = 0; k4 < 16; k4++) {
            float4 w0 = *(float4*)&Wt[(k4 * 4 + 0) * D + c0];
            float4 w1 = *(float4*)&Wt[(k4 * 4 + 1) * D + c0];
            float4 w2 = *(float4*)&Wt[(k4 * 4 + 2) * D + c0];
            float4 w3 = *(float4*)&Wt[(k4 * 4 + 3) * D + c0];
            #pragma unroll
            for (int jj = 0; jj < 8; jj++) {
                float4 cv = *(float4*)&Buf[(ng * 8 + jj) * D + k4 * 4];
                fma4(acc[jj], cv, w0, w1, w2, w3);
            }
        }
    }
    // h = relu(acc + b1) -> Buf (full 128 cols)
    {
        float4 b1v = *(const float4*)&cd1_b[c0];
        __syncthreads();   // all reads of Buf complete before overwrite
        #pragma unroll
        for (int jj = 0; jj < 8; jj++) {
            float4 r;
            r.x = fmaxf(acc[jj].x + b1v.x, 0.f);
            r.y = fmaxf(acc[jj].y + b1v.y, 0.f);
            r.z = fmaxf(acc[jj].z + b1v.z, 0.f);
            r.w = fmaxf(acc[jj].w + b1v.w, 0.f);
            *(float4*)&Buf[(ng * 8 + jj) * D + c0] = r;
            acc[jj] = make_float4(0.f, 0.f, 0.f, 0.f);
        }
    }
    // ---- GEMM2: h @ cd2_w (operand already in Buf) ----
    for (int kt = 0; kt < 2; kt++) {
        int k0 = kt * 64;
        __syncthreads();   // Wt free to restage; h writes visible (kt=0)
        const float4* Wg = (const float4*)(cd2_w + (size_t)k0 * D);
        float4* Wl = (float4*)Wt;
        #pragma unroll
        for (int i = 0; i < 8; i++) Wl[i * 256 + t] = Wg[i * 256 + t];
        __syncthreads();
        #pragma unroll 4
        for (int k4 = 0; k4 < 16; k4++) {
            float4 w0 = *(float4*)&Wt[(k4 * 4 + 0) * D + c0];
            float4 w1 = *(float4*)&Wt[(k4 * 4 + 1) * D + c0];
            float4 w2 = *(float4*)&Wt[(k4 * 4 + 2) * D + c0];
            float4 w3 = *(float4*)&Wt[(k4 * 4 + 3) * D + c0];
            #pragma unroll
            for (int jj = 0; jj < 8; jj++) {
                float4 cv = *(float4*)&Buf[(ng * 8 + jj) * D + k0 + k4 * 4];
                fma4(acc[jj], cv, w0, w1, w2, w3);
            }
        }
    }
    // cs = sigmoid(acc + b2), kept in registers (same (row,col) ownership)
    float4 cs[8];
    {
        float4 b2v = *(const float4*)&cd2_b[c0];
        #pragma unroll
        for (int jj = 0; jj < 8; jj++) {
            cs[jj].x = 1.f / (1.f + __expf(-(acc[jj].x + b2v.x)));
            cs[jj].y = 1.f / (1.f + __expf(-(acc[jj].y + b2v.y)));
            cs[jj].z = 1.f / (1.f + __expf(-(acc[jj].z + b2v.z)));
            cs[jj].w = 1.f / (1.f + __expf(-(acc[jj].w + b2v.w)));
            acc[jj] = make_float4(0.f, 0.f, 0.f, 0.f);
        }
    }
    // ---- GEMM3: (node_px + agg) @ int_w ----
    for (int kt = 0; kt < 2; kt++) {
        int k0 = kt * 64;
        __syncthreads();   // done reading Buf(h) / Wt
        const float4* Wg = (const float4*)(int_w + (size_t)k0 * D);
        float4* Wl = (float4*)Wt;
        #pragma unroll
        for (int i = 0; i < 8; i++) Wl[i * 256 + t] = Wg[i * 256 + t];
        #pragma unroll
        for (int i = 0; i < 4; i++) {
            int f = i * 256 + t;
            int n = f >> 4;
            int nn = n0 + n; if (nn >= N) nn = N - 1;
            float4 a4 = *(const float4*)&node_px[(size_t)nn * D + k0 + k4s * 4];
            float4 g4 = agg_otf(&bagg[(size_t)nn * A], AEr[kt]);
            float4 v = make_float4(a4.x + g4.x, a4.y + g4.y, a4.z + g4.z, a4.w + g4.w);
            *(float4*)&Buf[n * D + k4s * 4] = v;
        }
        __syncthreads();
        #pragma unroll 4
        for (int k4 = 0; k4 < 16; k4++) {
            float4 w0 = *(float4*)&Wt[(k4 * 4 + 0) * D + c0];
            float4 w1 = *(float4*)&Wt[(k4 * 4 + 1) * D + c0];
            float4 w2 = *(float4*)&Wt[(k4 * 4 + 2) * D + c0];
            float4 w3 = *(float4*)&Wt[(k4 * 4 + 3) * D + c0];
            #pragma unroll
            for (int jj = 0; jj < 8; jj++) {
                float4 cv = *(float4*)&Buf[(ng * 8 + jj) * D + k4 * 4];
                fma4(acc[jj], cv, w0, w1, w2, w3);
            }
        }
    }
    // ---- epilogue: final = node_px + cs * (acc + int_b) ----
    {
        float4 bi = *(const float4*)&int_b[c0];
        #pragma unroll
        for (int jj = 0; jj < 8; jj++) {
            int n = n0 + ng * 8 + jj;
            if (n < N) {
                float4 np = *(const float4*)&node_px[(size_t)n * D + c0];
                float4 r;
                r.x = np.x + cs[jj].x * (acc[jj].x + bi.x);
                r.y = np.y + cs[jj].y * (acc[jj].y + bi.y);
                r.z = np.z + cs[jj].z * (acc[jj].z + bi.z);
                r.w = np.w + cs[jj].w * (acc[jj].w + bi.w);
                *(float4*)&final_x[(size_t)n * D + c0] = r;
            }
        }
    }
}

extern "C" void kernel_launch(void* const* d_in, const int* in_sizes, int n_in,
                              void* d_out, int out_size, void* d_ws, size_t ws_size,
                              hipStream_t stream)
{
    const float* x           = (const float*)d_in[0];
    const float* anchor_node = (const float*)d_in[1];
    const float* attn_w      = (const float*)d_in[2];
    const float* attn_b      = (const float*)d_in[3];
    const float* anchor_edge = (const float*)d_in[4];
    const float* w_w         = (const float*)d_in[5];
    const float* w_b         = (const float*)d_in[6];
    const float* cd1_w       = (const float*)d_in[7];
    const float* cd1_b       = (const float*)d_in[8];
    const float* cd2_w       = (const float*)d_in[9];
    const float* cd2_b       = (const float*)d_in[10];
    const float* int_w       = (const float*)d_in[11];
    const float* int_b       = (const float*)d_in[12];
    const int*   ei          = (const int*)d_in[13];

    int N = in_sizes[0] / D;
    int E = in_sizes[13] / 2;

    float* out         = (float*)d_out;
    float* node_px     = out;                       // reuse final_x slot for node_px
    float* edge_prompt = out + (size_t)N * D;
    // workspace: only the tiny rank-A tables now
    float* bagg        = (float*)d_ws;              // N*A floats
    float* lsrc        = bagg + (size_t)N * A;      // N*A floats
    float* ldst        = bagg + (size_t)2 * N * A;  // N*A floats

    hipMemsetAsync(bagg, 0, (size_t)N * A * sizeof(float), stream);

    node_prompt_kernel<<<512, 256, 0, stream>>>(x, attn_w, attn_b, anchor_node, w_w,
                                                node_px, lsrc, ldst, N);
    edge_kernel<<<2048, 256, 0, stream>>>(ei, lsrc, ldst, w_b, anchor_edge,
                                          edge_prompt, bagg, E);

    int nb = (N + TM - 1) / TM;
    fused_tail_kernel<<<nb, 256, 0, stream>>>(node_px, bagg, anchor_edge,
                                              cd1_w, cd1_b, cd2_w, cd2_b,
                                              int_w, int_b, node_px, N);
}